// Round 1
// 397.298 us; speedup vs baseline: 1.1411x; 1.1411x over previous
//
#include <hip/hip_runtime.h>
#include <cstdint>
#include <cstddef>

// ============================================================================
// ResMLP fused kernel for MI355X (gfx950) — round 9
//
// Register-resident activations + 32x32x16 MFMA (y^T = W^T · h^T):
//  - Each wave owns 32 batch rows for the whole net. acc[5] f32x16 (80 VGPR),
//    fp32 residual resid[5] (80 VGPR). Batch index lives on lane&31 in BOTH
//    the MFMA D layout and the B-operand layout -> layer-to-layer handoff is
//    lane-local (4 v_cvt_pk_bf16_f32 per k-tile, nothing else).
//  - The D-row vs B-k index mismatch is folded into the WEIGHTS: prep stores
//    layer/head weights with k-order permuted as
//       khid = 32*(kt>>1) + 16*(kt&1) + 4*h + (j&3) + 8*(j>>2)
//    so resid regs pack directly into next layer's B fragment.
//  - LDS holds only weights: 1KB frag-blocks (lane*16 linear), staged with
//    global_load_lds and read with ds_read_b128 at lane*16 -> zero bank
//    conflicts (was 2.8e7 conflict-cycles).
//  - Half-image double buffer (2 x 25.6KB): stage next half at phase start,
//    compute 25 MFMAs, barrier. Staging drain is covered by the phase.
//  - Embed: x read HBM->regs (float4 x2 per k-tile; 784 = 49*16 exactly),
//    natural k-order weights; bias added at embed end; head stores direct.
// ============================================================================

typedef __attribute__((ext_vector_type(8))) short bfrag8;     // 8 x bf16
typedef __attribute__((ext_vector_type(16))) float f32x16;    // MFMA 32x32 acc
typedef __attribute__((ext_vector_type(4))) uint32_t u32x4;

#define MFMA32(a, b, c) __builtin_amdgcn_mfma_f32_32x32x16_bf16((a), (b), (c), 0, 0, 0)

#define NFRAG_TOTAL 1855   // 245 embed + 32*50 layer + 10 head 1KB frag-blocks

static __device__ __forceinline__ uint16_t f2bf16u(float v) {
    uint32_t u = __builtin_bit_cast(uint32_t, v);
    uint32_t r = u + 0x7FFFu + ((u >> 16) & 1u);
    return (uint16_t)(r >> 16);
}
static __device__ __forceinline__ uint32_t pack2_bf16(float lo, float hi) {
    return (uint32_t)f2bf16u(lo) | ((uint32_t)f2bf16u(hi) << 16);
}
static __device__ __forceinline__ uint32_t cvtpk(float lo, float hi) {
    uint32_t r;
    asm("v_cvt_pk_bf16_f32 %0, %1, %2" : "=v"(r) : "v"(lo), "v"(hi));
    return r;
}
// async global->LDS, 16B per lane; lds dest = wave-uniform base + lane*16
static __device__ __forceinline__ void gl_lds16(const void* g, void* l) {
    __builtin_amdgcn_global_load_lds(
        (const __attribute__((address_space(1))) uint32_t*)g,
        (__attribute__((address_space(3))) uint32_t*)l, 16, 0, 0);
}

// ---------------------------------------------------------------------------
// prep: build 1KB A-fragment blocks (W^T as MFMA A operand, bf16).
// Block fb, lane l (h=l>>5, m32=l&31), elem j (byte 2j of lane's 16B):
//   embed  (fb<245):   kt=fb/5, mt=fb%5,  k natural = kt*16 + h*8 + j
//   layer  (fb<1845):  k permuted: khid = 32*(kt>>1)+16*(kt&1)+4h+(j&3)+8*(j>>2)
//   head   (else):     same permuted k; m>=10 zero-padded
// ---------------------------------------------------------------------------
__global__ __launch_bounds__(256) void resmlp_prep(
    const float* __restrict__ embed_w, const float* __restrict__ layer_w,
    const float* __restrict__ head_w, uint16_t* __restrict__ ws)
{
    const int fb = blockIdx.x * 4 + (threadIdx.x >> 6);
    if (fb >= NFRAG_TOTAL) return;
    const int l = threadIdx.x & 63;
    const int h = l >> 5, m32 = l & 31;
    float v[8];
    if (fb < 245) {
        const int kt = fb / 5, mt = fb % 5;
        const int m = mt * 32 + m32;
        const int kb = kt * 16 + h * 8;
#pragma unroll
        for (int j = 0; j < 8; ++j)
            v[j] = embed_w[(size_t)(kb + j) * 160 + m];
    } else if (fb < 1845) {
        const int t = fb - 245, L = t / 50, r = t % 50, kt = r / 5, mt = r % 5;
        const int m = mt * 32 + m32;
        const float* W = layer_w + (size_t)L * 25600;
        const int kb = 32 * (kt >> 1) + 16 * (kt & 1) + 4 * h;
#pragma unroll
        for (int j = 0; j < 8; ++j)
            v[j] = W[(size_t)(kb + (j & 3) + 8 * (j >> 2)) * 160 + m];
    } else {
        const int kt = fb - 1845;
        const int kb = 32 * (kt >> 1) + 16 * (kt & 1) + 4 * h;
#pragma unroll
        for (int j = 0; j < 8; ++j)
            v[j] = (m32 < 10) ? head_w[(kb + (j & 3) + 8 * (j >> 2)) * 10 + m32] : 0.f;
    }
    u32x4 wv;
    wv.x = pack2_bf16(v[0], v[1]);
    wv.y = pack2_bf16(v[2], v[3]);
    wv.z = pack2_bf16(v[4], v[5]);
    wv.w = pack2_bf16(v[6], v[7]);
    *(u32x4*)((char*)ws + (size_t)fb * 1024 + l * 16) = wv;
}

// ---------------------------------------------------------------------------
// stage-unit table: 38 panels, two halves each.
//  u<5 embed chunks (50 blocks; chunk 4 has 45), u 5..36 layers (50), u=37 head (10)
// ---------------------------------------------------------------------------
struct StageP { int S, C, D; };
static __device__ __forceinline__ StageP stage_params(int u, int hf) {
    StageP p;
    if (u < 5)       { p.S = u * 50 + hf * 25;            p.C = (u == 4 && hf) ? 20 : 25; p.D = hf * 25600; }
    else if (u < 37) { p.S = 245 + (u - 5) * 50 + hf * 25; p.C = 25;                      p.D = hf * 25600; }
    else             { p.S = 1845 + hf * 5;                p.C = 5;                        p.D = hf * 5120;  }
    return p;
}

template<int K0, int K1>
static __device__ __forceinline__ void embed_loadx(const float* __restrict__ xb,
                                                   float4 (&xv)[10])
{
#pragma unroll
    for (int kt = K0; kt < K1; ++kt) {
        xv[2 * (kt - K0)]     = *(const float4*)(xb + kt * 16);
        xv[2 * (kt - K0) + 1] = *(const float4*)(xb + kt * 16 + 4);
    }
}

template<int K0, int K1>
static __device__ __forceinline__ void embed_mfma(const float4 (&xv)[10],
    const uint16_t* __restrict__ lds, f32x16 (&acc)[5], int lane8)
{
#pragma unroll
    for (int kt = K0; kt < K1; ++kt) {
        const float4 v0 = xv[2 * (kt - K0)], v1 = xv[2 * (kt - K0) + 1];
        u32x4 bw;
        bw.x = cvtpk(v0.x, v0.y);
        bw.y = cvtpk(v0.z, v0.w);
        bw.z = cvtpk(v1.x, v1.y);
        bw.w = cvtpk(v1.z, v1.w);
        const bfrag8 b = __builtin_bit_cast(bfrag8, bw);
#pragma unroll
        for (int mt = 0; mt < 5; ++mt) {
            const bfrag8 a = *(const bfrag8*)(lds + (kt * 5 + mt) * 512 + lane8);
            acc[mt] = MFMA32(a, b, acc[mt]);
        }
    }
}

template<int K0, int K1, int NMT>
static __device__ __forceinline__ void layer_mfma(
    const uint16_t* __restrict__ lds, f32x16 (&acc)[5],
    const f32x16 (&resid)[5], int lane8)
{
#pragma unroll
    for (int kt = K0; kt < K1; ++kt) {
        const int ms = kt >> 1, rb = (kt & 1) * 8;
        u32x4 bw;
        bw.x = cvtpk(resid[ms][rb + 0], resid[ms][rb + 1]);
        bw.y = cvtpk(resid[ms][rb + 2], resid[ms][rb + 3]);
        bw.z = cvtpk(resid[ms][rb + 4], resid[ms][rb + 5]);
        bw.w = cvtpk(resid[ms][rb + 6], resid[ms][rb + 7]);
        const bfrag8 b = __builtin_bit_cast(bfrag8, bw);
#pragma unroll
        for (int mt = 0; mt < NMT; ++mt) {
            const bfrag8 a = *(const bfrag8*)(lds + (kt * NMT + mt) * 512 + lane8);
            acc[mt] = MFMA32(a, b, acc[mt]);
        }
    }
}

// ---------------------------------------------------------------------------
__global__ __launch_bounds__(256, 2) void resmlp_main(
    const float* __restrict__ x,
    const float* __restrict__ embed_b,
    const float* __restrict__ head_b,
    const uint16_t* __restrict__ ws,
    float* __restrict__ out)
{
    extern __shared__ __align__(16) uint16_t lds[];   // 51200 B: 2 x 25.6KB halves
    const int tid  = threadIdx.x;
    const int wave = tid >> 6, lane = tid & 63;
    const int hi = lane >> 5, ln = lane & 31;
    const int lane8 = lane * 8;                       // u16 elems = lane*16 B
    const int batch = blockIdx.x * 128 + wave * 32 + ln;

    f32x16 acc[5], resid[5];
#pragma unroll
    for (int mt = 0; mt < 5; ++mt)
#pragma unroll
        for (int r = 0; r < 16; ++r) acc[mt][r] = 0.f;

    auto do_stage = [&](int u, int hf) {
        const StageP p = stage_params(u, hf);
        const char* src = (const char*)ws + (size_t)p.S * 1024 + lane * 16;
        char* dst = (char*)lds + p.D + lane * 16;
        for (int i = wave; i < p.C; i += 4)
            gl_lds16(src + (size_t)i * 1024, dst + i * 1024);
    };

    // ---- prologue: embed chunk 0, half A ----
    do_stage(0, 0);
    __syncthreads();

    // ---- embed: 5 chunks of 160 k (last effective 144), acc accumulates ----
    for (int c = 0; c < 5; ++c) {
        const float* xb = x + (size_t)batch * 784 + c * 160 + hi * 8;
        float4 xv[10];
        // phase A: x loads first (vmcnt FIFO), then stage own half B
        embed_loadx<0, 5>(xb, xv);
        do_stage(c, 1);
        embed_mfma<0, 5>(xv, lds, acc, lane8);
        __syncthreads();
        // phase B: stage next panel's half A
        if (c < 4) {
            embed_loadx<5, 10>(xb, xv);
            do_stage(c + 1, 0);
            embed_mfma<5, 10>(xv, lds, acc, lane8);
        } else {
            embed_loadx<5, 9>(xb, xv);
            do_stage(5, 0);
            embed_mfma<5, 9>(xv, lds, acc, lane8);
        }
        __syncthreads();
    }

    // ---- 32 residual layers ----
    for (int L = 0; L < 32; ++L) {
        do_stage(5 + L, 1);
        if (L == 0) {
            // resid = embed acc + bias (D layout: h' = (r&3)+8*(r>>2)+4*hi)
#pragma unroll
            for (int mt = 0; mt < 5; ++mt)
#pragma unroll
                for (int q2 = 0; q2 < 4; ++q2) {
                    const float4 b4 = *(const float4*)(embed_b + mt * 32 + q2 * 8 + hi * 4);
                    resid[mt][q2 * 4 + 0] = acc[mt][q2 * 4 + 0] + b4.x;
                    resid[mt][q2 * 4 + 1] = acc[mt][q2 * 4 + 1] + b4.y;
                    resid[mt][q2 * 4 + 2] = acc[mt][q2 * 4 + 2] + b4.z;
                    resid[mt][q2 * 4 + 3] = acc[mt][q2 * 4 + 3] + b4.w;
                }
        } else {
#pragma unroll
            for (int mt = 0; mt < 5; ++mt)
#pragma unroll
                for (int r = 0; r < 16; ++r)
                    resid[mt][r] += fmaxf(acc[mt][r], 0.f);
        }
#pragma unroll
        for (int mt = 0; mt < 5; ++mt)
#pragma unroll
            for (int r = 0; r < 16; ++r) acc[mt][r] = 0.f;

        layer_mfma<0, 5, 5>(lds, acc, resid, lane8);
        __syncthreads();
        do_stage(L < 31 ? 6 + L : 37, 0);
        layer_mfma<5, 10, 5>(lds, acc, resid, lane8);
        __syncthreads();
    }

    // ---- head (10 kt, 1 m-tile, classes 0..9) ----
    do_stage(37, 1);
#pragma unroll
    for (int mt = 0; mt < 5; ++mt)
#pragma unroll
        for (int r = 0; r < 16; ++r)
            resid[mt][r] += fmaxf(acc[mt][r], 0.f);
#pragma unroll
    for (int r = 0; r < 16; ++r) acc[0][r] = 0.f;

    layer_mfma<0, 5, 1>(lds, acc, resid, lane8);
    __syncthreads();
    layer_mfma<5, 10, 1>(lds, acc, resid, lane8);

    // epilogue: D row h' = (r&3)+8*(r>>2)+4*hi -> class index (h'<10)
    float* op = out + (size_t)batch * 10;
    if (hi == 0) {
        op[0] = acc[0][0] + head_b[0];
        op[1] = acc[0][1] + head_b[1];
        op[2] = acc[0][2] + head_b[2];
        op[3] = acc[0][3] + head_b[3];
        op[8] = acc[0][4] + head_b[8];
        op[9] = acc[0][5] + head_b[9];
    } else {
        op[4] = acc[0][0] + head_b[4];
        op[5] = acc[0][1] + head_b[5];
        op[6] = acc[0][2] + head_b[6];
        op[7] = acc[0][3] + head_b[7];
    }
}

// ---------------------------------------------------------------------------
extern "C" void kernel_launch(void* const* d_in, const int* in_sizes, int n_in,
                              void* d_out, int out_size, void* d_ws, size_t ws_size,
                              hipStream_t stream) {
    (void)in_sizes; (void)n_in; (void)out_size; (void)ws_size;
    const float* x       = (const float*)d_in[0];
    const float* embed_w = (const float*)d_in[1];
    const float* embed_b = (const float*)d_in[2];
    const float* layer_w = (const float*)d_in[3];
    const float* head_w  = (const float*)d_in[4];
    const float* head_b  = (const float*)d_in[5];
    float* out = (float*)d_out;

    uint16_t* ws = (uint16_t*)d_ws;   // 1855 KB of frag-blocks

    const int dynLds = 51200;
    (void)hipFuncSetAttribute((const void*)resmlp_main,
                              hipFuncAttributeMaxDynamicSharedMemorySize, dynLds);

    resmlp_prep<<<(NFRAG_TOTAL + 3) / 4, 256, 0, stream>>>(embed_w, layer_w, head_w, ws);
    resmlp_main<<<512, 256, dynLds, stream>>>(x, embed_b, head_b, ws, out);
}